// Round 10
// baseline (522.117 us; speedup 1.0000x reference)
//
#include <hip/hip_runtime.h>
#include <hip/hip_bf16.h>
#include <math.h>

// ---------- types & helpers ----------
typedef float  f32x4  __attribute__((ext_vector_type(4)));
typedef __bf16 bf16x8 __attribute__((ext_vector_type(8)));

__device__ __forceinline__ unsigned short f2bf(float f){
  union { float f; unsigned u; } v; v.f = f;
  unsigned u = v.u;
  return (unsigned short)((u + 0x7FFFu + ((u >> 16) & 1u)) >> 16);
}
__device__ __forceinline__ float bf2f(unsigned short h){
  union { unsigned u; float f; } v; v.u = ((unsigned)h) << 16;
  return v.f;
}
__device__ __forceinline__ void gload_lds16(const void* g, void* l){
  __builtin_amdgcn_global_load_lds((__attribute__((address_space(1))) void*)g,
                                   (__attribute__((address_space(3))) void*)l, 16, 0, 0);
}
__device__ __forceinline__ float sigmoidf_(float x){ return 1.f / (1.f + expf(-x)); }

// ---------- prep: split X into [hi | lo | hi] bf16, K 1024 -> 3072 ----------
__global__ __launch_bounds__(256)
void split_x_kernel(const float* __restrict__ X, unsigned short* __restrict__ A){
  for (int i = blockIdx.x*256 + threadIdx.x; i < 8192*1024; i += gridDim.x*256){
    int row = i >> 10, col = i & 1023;
    float x = X[i];
    unsigned short h = f2bf(x);
    unsigned short l = f2bf(x - bf2f(h));
    unsigned short* Ar = A + (size_t)row*3072 + col;
    Ar[0]    = h;   // hi
    Ar[1024] = l;   // lo
    Ar[2048] = h;   // hi (pairs with w_lo)
  }
}

// ---------- prep: LDS-tiled 64x64 transpose/convert for all weights ----------
__global__ __launch_bounds__(256)
void prep_tiles(const float* __restrict__ enc_w, const float* __restrict__ dec_w,
                const float* __restrict__ e_w1, const float* __restrict__ e_w2,
                const float* __restrict__ c2s_w,
                unsigned short* __restrict__ BtE, unsigned short* __restrict__ decT,
                unsigned short* __restrict__ W1T, unsigned short* __restrict__ W2T,
                unsigned short* __restrict__ c2sT)
{
  __shared__ unsigned tile[64*65];   // packed hi|lo<<16, transposed, pad 65
  const int t = threadIdx.x;
  const int b = blockIdx.x;

  const float* src; long sbase; int sld, r0, c0;
  if (b < 512)        { src = enc_w; sbase = 0;                    sld = 2048; r0 = (b>>5)*64;       c0 = (b&31)*64; }
  else if (b < 1024)  { int q=b-512;  src = dec_w; sbase = 0;      sld = 1024; r0 = (q>>4)*64;       c0 = (q&15)*64; }
  else if (b < 1152)  { int q=b-1024; src = e_w1;  sbase = (long)(q>>4)*65536; sld = 1024; r0 = 0;   c0 = (q&15)*64; }
  else if (b < 1280)  { int q=b-1152; src = e_w2;  sbase = (long)(q>>4)*65536; sld = 64;   r0 = (q&15)*64; c0 = 0; }
  else                { int q=b-1280; src = c2s_w; sbase = 0;      sld = 2048; r0 = 0;              c0 = q*64; }

  #pragma unroll
  for (int it = 0; it < 4; ++it){
    int r  = it*16 + (t>>4);
    int c4 = (t&15)*4;
    float4 v = *(const float4*)&src[sbase + (long)(r0+r)*sld + c0 + c4];
    float vv[4] = {v.x, v.y, v.z, v.w};
    #pragma unroll
    for (int e = 0; e < 4; ++e){
      unsigned short h = f2bf(vv[e]);
      unsigned short l = f2bf(vv[e] - bf2f(h));
      tile[(c4+e)*65 + r] = (unsigned)h | ((unsigned)l << 16);
    }
  }
  __syncthreads();

  #pragma unroll
  for (int it = 0; it < 2; ++it){
    int c  = it*32 + (t>>3);
    int kc = (t&7)*8;
    unsigned short hi8[8], lo8[8];
    #pragma unroll
    for (int e = 0; e < 8; ++e){
      unsigned p = tile[c*65 + kc + e];
      hi8[e] = (unsigned short)(p & 0xFFFFu);
      lo8[e] = (unsigned short)(p >> 16);
    }
    if (b < 512){
      unsigned short* dst = BtE + (size_t)(c0 + c)*3072 + r0 + kc;
      *(uint4*)(dst)        = *(const uint4*)hi8;
      *(uint4*)(dst + 1024) = *(const uint4*)hi8;
      *(uint4*)(dst + 2048) = *(const uint4*)lo8;
    } else if (b < 1024){
      *(uint4*)(decT + (size_t)(c0 + c)*2048 + r0 + kc) = *(const uint4*)hi8;
    } else if (b < 1152){
      int e = (b-1024) >> 4;
      *(uint4*)(W1T + ((size_t)e<<16) + (size_t)(c0 + c)*64 + kc) = *(const uint4*)hi8;
    } else if (b < 1280){
      int e = (b-1152) >> 4;
      *(uint4*)(W2T + ((size_t)e<<16) + (size_t)(c0 + c)*1024 + r0 + kc) = *(const uint4*)hi8;
    } else {
      *(uint4*)(c2sT + (size_t)(c0 + c)*64 + kc) = *(const uint4*)hi8;
    }
  }
}

// ---------- deep-pipelined 256xBN GEMM (T3/T4): BK=32, 4-slot circular LDS, ----------
// counted vmcnt (never 0 in steady loop), raw s_barrier, setprio around MFMA.
// C = sigmoid(A[M,K] @ Bt[N,K]^T + bias), f32 out. Grid = (M/256)*(N/BN), 512 thr.
// Loads/tile/thread LPT = 2 (A) + BN/128 (B); steady wait = 2*LPT, tail LPT, 0.
template<int BN>
__global__ __launch_bounds__(512)
void gemm8(const unsigned short* __restrict__ A, const unsigned short* __restrict__ Bt,
           const float* __restrict__ bias, float* __restrict__ C,
           int M, int N, int K)
{
  __shared__ alignas(16) char AsB[4][16384];     // [slot][256 rows x 32 bf16 (64B)]
  __shared__ alignas(16) char BsB[4][BN*64];     // [slot][BN rows x 32 bf16]
  const int t = threadIdx.x, w = t >> 6, lane = t & 63;
  const int nbn = N / BN;
  const int qq = gridDim.x >> 3, bid = (int)blockIdx.x;
  const int sbk = (bid & 7) * qq + (bid >> 3);   // bijective XCD swizzle (grid%8==0)
  const int bm = sbk / nbn, bn = sbk % nbn;
  const int wm = w >> 2, wn = w & 3;             // 2 x 4 wave grid
  constexpr int NR = BN / 64;                    // N fragments per wave (col width BN/4)

  f32x4 acc[8][NR];
  #pragma unroll
  for (int m=0;m<8;++m)
    #pragma unroll
    for (int n=0;n<NR;++n) acc[m][n] = (f32x4){0.f,0.f,0.f,0.f};

  const size_t Kb = (size_t)K * 2;
  const char* Ab = (const char*)A  + (size_t)(bm*256) * Kb;
  const char* Bb = (const char*)Bt + (size_t)(bn*BN) * Kb;
  const int nt = K >> 5;

  auto STAGE = [&](int kt){
    char* Ad = AsB[kt & 3]; char* Bd = BsB[kt & 3];
    #pragma unroll
    for (int i = 0; i < 2; ++i){
      int chunk = w*2 + i;
      int row   = chunk*16 + (lane >> 2);
      int sw    = (((lane & 3) ^ ((row >> 1) & 3)) << 4);
      gload_lds16(Ab + (size_t)row*Kb + (size_t)kt*64 + sw, Ad + chunk*1024);
    }
    #pragma unroll
    for (int i = 0; i < BN/128; ++i){
      int chunk = w*(BN/128) + i;
      int row   = chunk*16 + (lane >> 2);
      int sw    = (((lane & 3) ^ ((row >> 1) & 3)) << 4);
      gload_lds16(Bb + (size_t)row*Kb + (size_t)kt*64 + sw, Bd + chunk*1024);
    }
  };

  STAGE(0); STAGE(1); STAGE(2);
  if constexpr (BN == 256) asm volatile("s_waitcnt vmcnt(8)" ::: "memory");
  else                     asm volatile("s_waitcnt vmcnt(6)" ::: "memory");
  __builtin_amdgcn_s_barrier();

  for (int t0 = 0; t0 < nt; ++t0){
    if (t0 + 3 < nt) STAGE(t0 + 3);        // slot (t0+3)&3 retired at iter t0-1 barrier
    const char* Ar = AsB[t0 & 3];
    const char* Br = BsB[t0 & 3];
    bf16x8 af[8], bg[NR];
    #pragma unroll
    for (int m = 0; m < 8; ++m){
      int ra = wm*128 + m*16 + (lane & 15);
      af[m] = *(const bf16x8*)(Ar + ra*64 + ((((lane>>4) ^ ((ra>>1)&3))) << 4));
    }
    #pragma unroll
    for (int n = 0; n < NR; ++n){
      int rb = wn*(BN/4) + n*16 + (lane & 15);
      bg[n] = *(const bf16x8*)(Br + rb*64 + ((((lane>>4) ^ ((rb>>1)&3))) << 4));
    }
    __builtin_amdgcn_s_setprio(1);
    #pragma unroll
    for (int m = 0; m < 8; ++m)
      #pragma unroll
      for (int n = 0; n < NR; ++n)
        acc[m][n] = __builtin_amdgcn_mfma_f32_16x16x32_bf16(af[m], bg[n], acc[m][n], 0, 0, 0);
    __builtin_amdgcn_s_setprio(0);
    // counted wait: retire exactly tile t0+1's loads (issued 3 iters ago)
    if (t0 + 3 < nt){
      if constexpr (BN == 256) asm volatile("s_waitcnt vmcnt(8)" ::: "memory");
      else                     asm volatile("s_waitcnt vmcnt(6)" ::: "memory");
    } else if (t0 + 2 < nt){
      if constexpr (BN == 256) asm volatile("s_waitcnt vmcnt(4)" ::: "memory");
      else                     asm volatile("s_waitcnt vmcnt(3)" ::: "memory");
    } else {
      asm volatile("s_waitcnt vmcnt(0)" ::: "memory");
    }
    __builtin_amdgcn_s_barrier();
  }

  const int mrow0 = bm*256 + wm*128;
  const int ncol0 = bn*BN + wn*(BN/4);
  #pragma unroll
  for (int m = 0; m < 8; ++m){
    int row = mrow0 + m*16 + ((lane>>4)<<2);
    #pragma unroll
    for (int n = 0; n < NR; ++n){
      int col = ncol0 + n*16 + (lane & 15);
      float bv = bias[col];
      #pragma unroll
      for (int r = 0; r < 4; ++r){
        float v = sigmoidf_(acc[m][n][r] + bv);
        C[(size_t)(row + r)*N + col] = v;
      }
    }
  }
}

// ---------- 128x128 bf16 GEMM (m97 structure) for c2s ----------
template<int SIG, int OBF>
__global__ __launch_bounds__(256)
void gemm_bt(const unsigned short* __restrict__ A, const unsigned short* __restrict__ Bt,
             const float* __restrict__ bias, void* __restrict__ C,
             int M, int N, int K)
{
  __shared__ alignas(16) unsigned short As[128*64];
  __shared__ alignas(16) unsigned short Bs[128*64];
  const int t = threadIdx.x;
  const int wid = t >> 6, lane = t & 63;
  const int nbn = N >> 7;
  const int q = gridDim.x >> 3;
  const int bid = (int)blockIdx.x;
  const int sb = (bid & 7) * q + (bid >> 3);
  const int bm = sb / nbn, bn = sb % nbn;
  const int wm = wid >> 1, wn = wid & 1;

  f32x4 acc[4][4];
  #pragma unroll
  for (int i=0;i<4;++i)
    #pragma unroll
    for (int j=0;j<4;++j) acc[i][j] = (f32x4){0.f,0.f,0.f,0.f};

  const size_t Kb = (size_t)K * 2;
  const char* Ab = (const char*)A  + (size_t)(bm*128) * Kb;
  const char* Bb = (const char*)Bt + (size_t)(bn*128) * Kb;

  for (int k0 = 0; k0 < K; k0 += 64){
    #pragma unroll
    for (int i = 0; i < 4; ++i){
      int L  = ((i*4 + wid) << 10) + (lane << 4);
      int r  = L >> 7;
      int cb = L & 127;
      int sb2 = cb ^ ((r & 7) << 4);
      gload_lds16(Ab + (size_t)r*Kb + (size_t)k0*2 + sb2, (char*)As + ((i*4+wid)<<10));
      gload_lds16(Bb + (size_t)r*Kb + (size_t)k0*2 + sb2, (char*)Bs + ((i*4+wid)<<10));
    }
    __syncthreads();
    #pragma unroll
    for (int ks = 0; ks < 64; ks += 32){
      bf16x8 af[4], bg[4];
      const int cb = ks*2 + ((lane >> 4) << 4);
      #pragma unroll
      for (int i = 0; i < 4; ++i){
        int ra = wm*64 + i*16 + (lane & 15);
        af[i] = *(const bf16x8*)((const char*)As + (ra<<7) + (cb ^ ((ra&7)<<4)));
        int rb = wn*64 + i*16 + (lane & 15);
        bg[i] = *(const bf16x8*)((const char*)Bs + (rb<<7) + (cb ^ ((rb&7)<<4)));
      }
      #pragma unroll
      for (int i = 0; i < 4; ++i)
        #pragma unroll
        for (int j = 0; j < 4; ++j)
          acc[i][j] = __builtin_amdgcn_mfma_f32_16x16x32_bf16(af[i], bg[j], acc[i][j], 0, 0, 0);
    }
    __syncthreads();
  }

  const int mrow0 = bm*128 + wm*64;
  const int ncol0 = bn*128 + wn*64;
  #pragma unroll
  for (int i = 0; i < 4; ++i){
    int row = mrow0 + i*16 + ((lane>>4)<<2);
    #pragma unroll
    for (int j = 0; j < 4; ++j){
      int col = ncol0 + j*16 + (lane & 15);
      float bv = bias[col];
      #pragma unroll
      for (int r = 0; r < 4; ++r){
        float v = acc[i][j][r] + bv;
        if (SIG) v = sigmoidf_(v);
        if (OBF) ((unsigned short*)C)[(size_t)(row + r)*N + col] = f2bf(v);
        else     ((float*)C)[(size_t)(row + r)*N + col] = v;
      }
    }
  }
}

// ---------- s2c (exact fp32), lane=token, 16-way K-split ----------
__global__ __launch_bounds__(256)
void s2c_split(const float* __restrict__ spikes, const float* __restrict__ w,
               float* __restrict__ part)
{
  __shared__ float wS[4][64*64];
  const int t = threadIdx.x, wid = t >> 6, lane = t & 63;
  const int tg = blockIdx.x >> 2;
  const int ck = ((blockIdx.x & 3) << 2) | wid;
  const int tok = tg*64 + lane;
  const int k0 = ck * 128;

  float acc[64];
  #pragma unroll
  for (int j=0;j<64;++j) acc[j] = 0.f;

  const float* srow = spikes + (size_t)tok*2048 + k0;
  float* wsp = wS[wid];

  for (int half = 0; half < 2; ++half){
    const float* gsrc = w + (size_t)(k0 + half*64)*64;
    #pragma unroll
    for (int it = 0; it < 16; ++it){
      int idx = (it*64 + lane)*4;
      *(float4*)&wsp[idx] = *(const float4*)&gsrc[idx];
    }
    #pragma unroll 2
    for (int kq = 0; kq < 16; ++kq){
      float4 s4 = *(const float4*)&srow[half*64 + kq*4];
      const float sv[4] = {s4.x, s4.y, s4.z, s4.w};
      #pragma unroll
      for (int ki = 0; ki < 4; ++ki){
        const float* wrow = &wsp[(kq*4+ki)*64];
        #pragma unroll
        for (int j4 = 0; j4 < 16; ++j4){
          float4 wv = *(const float4*)&wrow[j4*4];
          acc[j4*4+0] += sv[ki] * wv.x;
          acc[j4*4+1] += sv[ki] * wv.y;
          acc[j4*4+2] += sv[ki] * wv.z;
          acc[j4*4+3] += sv[ki] * wv.w;
        }
      }
    }
  }
  float* po = part + ((size_t)ck*8192 + tok)*64;
  #pragma unroll
  for (int j4 = 0; j4 < 16; ++j4){
    float4 o; o.x = acc[j4*4+0]; o.y = acc[j4*4+1]; o.z = acc[j4*4+2]; o.w = acc[j4*4+3];
    *(float4*)&po[j4*4] = o;
  }
}

__global__ __launch_bounds__(256)
void s2c_reduce(const float* __restrict__ part, const float* __restrict__ bias,
                float* __restrict__ cont, unsigned short* __restrict__ contbf)
{
  int i4 = blockIdx.x*256 + threadIdx.x;
  int base = i4 * 4;
  float4 a = {0.f,0.f,0.f,0.f};
  #pragma unroll
  for (int c = 0; c < 16; ++c){
    float4 p = *(const float4*)&part[(size_t)c*524288 + base];
    a.x += p.x; a.y += p.y; a.z += p.z; a.w += p.w;
  }
  int j0 = base & 63;
  float4 b = *(const float4*)&bias[j0];
  a.x += b.x; a.y += b.y; a.z += b.z; a.w += b.w;
  *(float4*)&cont[base] = a;
  unsigned short h0 = f2bf(a.x), h1 = f2bf(a.y), h2 = f2bf(a.z), h3 = f2bf(a.w);
  unsigned u0 = ((unsigned)h1 << 16) | h0;
  unsigned u1 = ((unsigned)h3 << 16) | h2;
  uint2 u; u.x = u0; u.y = u1;
  *(uint2*)&contbf[base] = u;
}

// ---------- router: MLP -> logits -> top2 -> renormalized dense comb[N,8] (fp32) ----------
__global__ __launch_bounds__(256)
void router_kernel(const float* __restrict__ cont, const float* __restrict__ w1,
                   const float* __restrict__ b1, const float* __restrict__ w2,
                   const float* __restrict__ b2, float* __restrict__ comb)
{
  __shared__ float w1s[64*64];
  __shared__ float w2s[64*8];
  __shared__ float b1s[64], b2s[8];
  __shared__ float rhs[4][64];
  const int t = threadIdx.x;
  for (int i = t; i < 64*64; i += 256) w1s[i] = w1[i];
  for (int i = t; i < 64*8;  i += 256) w2s[i] = w2[i];
  if (t < 64) b1s[t] = b1[t];
  if (t < 8)  b2s[t] = b2[t];
  __syncthreads();
  const int wid = t >> 6, lane = t & 63;
  const int gw = blockIdx.x*4 + wid, nw = gridDim.x*4;
  for (int n = gw; n < 8192; n += nw){
    float cv = cont[(size_t)n*64 + lane];
    float rh = b1s[lane];
    #pragma unroll
    for (int d = 0; d < 64; ++d){
      float cd = __shfl(cv, d);
      rh += cd * w1s[d*64 + lane];
    }
    rh = fmaxf(rh, 0.f);
    rhs[wid][lane] = rh;
    __syncthreads();
    float lg[8];
    #pragma unroll
    for (int e = 0; e < 8; ++e) lg[e] = b2s[e];
    for (int jj = 0; jj < 64; ++jj){
      float r = rhs[wid][jj];
      #pragma unroll
      for (int e = 0; e < 8; ++e) lg[e] += r * w2s[jj*8 + e];
    }
    int i1 = 0; float m1 = lg[0];
    #pragma unroll
    for (int e = 1; e < 8; ++e) if (lg[e] > m1){ m1 = lg[e]; i1 = e; }
    int i2 = -1; float m2 = -3.4e38f;
    #pragma unroll
    for (int e = 0; e < 8; ++e) if (e != i1 && lg[e] > m2){ m2 = lg[e]; i2 = e; }
    float e2 = expf(m2 - m1);
    float wA = 1.f / (1.f + e2);
    float wB = e2 / (1.f + e2);
    if (lane < 8) comb[(size_t)n*8 + lane] = (lane == i1) ? wA : ((lane == i2) ? wB : 0.f);
    __syncthreads();
  }
}

// ---------- dense fused expert compute (bf16 MFMA), partial over expert-pair groups ----------
__global__ __launch_bounds__(256)
void expert_kernel(const unsigned short* __restrict__ contbf, const float* __restrict__ comb,
                   const unsigned short* __restrict__ W1T, const unsigned short* __restrict__ W2T,
                   const float* __restrict__ e_b1, const float* __restrict__ e_b2,
                   float* __restrict__ part)
{
  __shared__ alignas(16) unsigned short contS[64*64];
  __shared__ alignas(16) unsigned short w1S[64*64];
  __shared__ alignas(16) unsigned short w2S[64*64];
  __shared__ alignas(16) unsigned short ehS[64*64];
  __shared__ float combS[64*8];
  const int t = threadIdx.x, wid = t >> 6, lane = t & 63;
  const int tb = blockIdx.x >> 2, z = blockIdx.x & 3;
  const int tok0 = tb * 64;

  #pragma unroll
  for (int it = 0; it < 2; ++it){
    int li = (it*256 + t)*8;
    int r = li >> 6, c = li & 63;
    uint4 v = *(const uint4*)(contbf + (size_t)(tok0 + r)*64 + c);
    *(uint4*)((char*)contS + (r<<7) + ((c*2) ^ ((r&7)<<4))) = v;
  }
  for (int i = t; i < 512; i += 256) combS[i] = comb[(size_t)tok0*8 + i];

  f32x4 macc[4];
  #pragma unroll
  for (int j=0;j<4;++j) macc[j] = (f32x4){0.f,0.f,0.f,0.f};

  for (int ei = 0; ei < 2; ++ei){
    const int e = z*2 + ei;
    f32x4 eo[4];
    #pragma unroll
    for (int j=0;j<4;++j) eo[j] = (f32x4){0.f,0.f,0.f,0.f};

    for (int hc = 0; hc < 16; ++hc){
      const int h0 = hc*64;
      __syncthreads();
      #pragma unroll
      for (int it = 0; it < 2; ++it){
        int li = (it*256 + t)*8;
        int r = li >> 6, c = li & 63;
        uint4 v1 = *(const uint4*)(W1T + ((size_t)e<<16) + (size_t)(h0+r)*64 + c);
        *(uint4*)((char*)w1S + (r<<7) + ((c*2) ^ ((r&7)<<4))) = v1;
        uint4 v2 = *(const uint4*)(W2T + ((size_t)e<<16) + (size_t)r*1024 + h0 + c);
        *(uint4*)((char*)w2S + (r<<7) + ((c*2) ^ ((r&7)<<4))) = v2;
      }
      __syncthreads();
      f32x4 eh[4];
      #pragma unroll
      for (int j=0;j<4;++j) eh[j] = (f32x4){0.f,0.f,0.f,0.f};
      #pragma unroll
      for (int ks = 0; ks < 64; ks += 32){
        const int cb = ks*2 + ((lane>>4)<<4);
        int ra = wid*16 + (lane & 15);
        bf16x8 av = *(const bf16x8*)((const char*)contS + (ra<<7) + (cb ^ ((ra&7)<<4)));
        #pragma unroll
        for (int j=0;j<4;++j){
          int rb = j*16 + (lane & 15);
          bf16x8 bv = *(const bf16x8*)((const char*)w1S + (rb<<7) + (cb ^ ((rb&7)<<4)));
          eh[j] = __builtin_amdgcn_mfma_f32_16x16x32_bf16(av, bv, eh[j], 0, 0, 0);
        }
      }
      #pragma unroll
      for (int j=0;j<4;++j){
        int colh = j*16 + (lane & 15);
        float b1v = e_b1[e*1024 + h0 + colh];
        #pragma unroll
        for (int r=0;r<4;++r){
          int rowt = wid*16 + ((lane>>4)<<2) + r;
          float v = fmaxf(eh[j][r] + b1v, 0.f);
          *(unsigned short*)((char*)ehS + (rowt<<7) + ((colh*2) ^ ((rowt&7)<<4))) = f2bf(v);
        }
      }
      __syncthreads();
      #pragma unroll
      for (int ks = 0; ks < 64; ks += 32){
        const int cb = ks*2 + ((lane>>4)<<4);
        int ra = wid*16 + (lane & 15);
        bf16x8 av = *(const bf16x8*)((const char*)ehS + (ra<<7) + (cb ^ ((ra&7)<<4)));
        #pragma unroll
        for (int j=0;j<4;++j){
          int rb = j*16 + (lane & 15);
          bf16x8 bv = *(const bf16x8*)((const char*)w2S + (rb<<7) + (cb ^ ((rb&7)<<4)));
          eo[j] = __builtin_amdgcn_mfma_f32_16x16x32_bf16(av, bv, eo[j], 0, 0, 0);
        }
      }
    }
    #pragma unroll
    for (int j=0;j<4;++j){
      int col = j*16 + (lane & 15);
      float b2v = e_b2[e*64 + col];
      #pragma unroll
      for (int r=0;r<4;++r){
        int rowt = wid*16 + ((lane>>4)<<2) + r;
        float w = combS[rowt*8 + e];
        macc[j][r] += w * (eo[j][r] + b2v);
      }
    }
  }
  #pragma unroll
  for (int j=0;j<4;++j){
    int col = j*16 + (lane & 15);
    #pragma unroll
    for (int r=0;r<4;++r){
      int rowt = wid*16 + ((lane>>4)<<2) + r;
      part[((size_t)z*8192 + tok0 + rowt)*64 + col] = macc[j][r];
    }
  }
}

__global__ __launch_bounds__(256)
void reduce_moe(const float* __restrict__ part, unsigned short* __restrict__ moebf){
  int i = blockIdx.x*256 + threadIdx.x;
  if (i < 8192*64){
    float v = part[i] + part[i + 524288] + part[i + 2*524288] + part[i + 3*524288];
    moebf[i] = f2bf(v);
  }
}

// ---------- LayerNorm over dec rows ----------
__global__ __launch_bounds__(256)
void ln_kernel(const float* __restrict__ dec, const float* __restrict__ g,
               const float* __restrict__ b, float* __restrict__ out){
  const int wid = threadIdx.x >> 6, lane = threadIdx.x & 63;
  const int row = blockIdx.x*4 + wid;
  const float4* x4 = (const float4*)(dec + (size_t)row*1024);
  float4 v[4]; float s = 0.f, s2 = 0.f;
  #pragma unroll
  for (int i=0;i<4;++i){
    v[i] = x4[lane + i*64];
    s  += (v[i].x + v[i].y) + (v[i].z + v[i].w);
    s2 += (v[i].x*v[i].x + v[i].y*v[i].y) + (v[i].z*v[i].z + v[i].w*v[i].w);
  }
  #pragma unroll
  for (int o = 32; o > 0; o >>= 1){ s += __shfl_xor(s, o); s2 += __shfl_xor(s2, o); }
  float mu  = s * (1.f/1024.f);
  float var = s2 * (1.f/1024.f) - mu*mu;
  float inv = rsqrtf(var + 1e-5f);
  float4* o4 = (float4*)(out + (size_t)row*1024);
  #pragma unroll
  for (int i=0;i<4;++i){
    int c0 = (lane + i*64)*4;
    float4 r;
    r.x = (v[i].x - mu)*inv*g[c0+0] + b[c0+0];
    r.y = (v[i].y - mu)*inv*g[c0+1] + b[c0+1];
    r.z = (v[i].z - mu)*inv*g[c0+2] + b[c0+2];
    r.w = (v[i].w - mu)*inv*g[c0+3] + b[c0+3];
    o4[lane + i*64] = r;
  }
}

// ---------- launch ----------
extern "C" void kernel_launch(void* const* d_in, const int* in_sizes, int n_in,
                              void* d_out, int out_size, void* d_ws, size_t ws_size,
                              hipStream_t stream)
{
  (void)in_sizes; (void)n_in; (void)out_size; (void)ws_size;
  const float* X     = (const float*)d_in[0];
  const float* enc_w = (const float*)d_in[1];
  const float* enc_b = (const float*)d_in[2];
  const float* s2c_w = (const float*)d_in[3];
  const float* s2c_b = (const float*)d_in[4];
  const float* r_w1  = (const float*)d_in[5];
  const float* r_b1  = (const float*)d_in[6];
  const float* r_w2  = (const float*)d_in[7];
  const float* r_b2  = (const float*)d_in[8];
  const float* e_w1  = (const float*)d_in[9];
  const float* e_b1  = (const float*)d_in[10];
  const float* e_w2  = (const float*)d_in[11];
  const float* e_b2  = (const float*)d_in[12];
  const float* c2s_w = (const float*)d_in[13];
  const float* c2s_b = (const float*)d_in[14];
  const float* dec_w = (const float*)d_in[15];
  const float* dec_b = (const float*)d_in[16];
  const float* ln_g  = (const float*)d_in[17];
  const float* ln_b  = (const float*)d_in[18];

  char* ws = (char*)d_ws;
  size_t off = 0;
  auto alloc = [&](size_t bytes){ void* p = ws + off; off += (bytes + 255) & ~(size_t)255; return p; };
  unsigned short* Axs    = (unsigned short*)alloc(8192ULL*3072*2);  // split X; reused as s2c part & rates
  unsigned short* BtE    = (unsigned short*)alloc(2048ULL*3072*2);
  float*          spikes = (float*)alloc(8192ULL*2048*4);           // later reused as dec f32
  float*          cont   = (float*)alloc(8192ULL*64*4);
  unsigned short* contbf = (unsigned short*)alloc(8192ULL*64*2);
  float*          comb   = (float*)alloc(8192ULL*8*4);
  unsigned short* W1T    = (unsigned short*)alloc(8ULL*1024*64*2);
  unsigned short* W2T    = (unsigned short*)alloc(8ULL*64*1024*2);
  unsigned short* moebf  = (unsigned short*)alloc(8192ULL*64*2);
  unsigned short* c2sT   = (unsigned short*)alloc(2048ULL*64*2);
  unsigned short* decT   = (unsigned short*)alloc(1024ULL*2048*2);
  float*          part   = (float*)Axs;
  unsigned short* rates  = Axs;
  float*          decf   = spikes;
  float*          outp   = (float*)d_out;

  split_x_kernel<<<dim3(4096), dim3(256), 0, stream>>>(X, Axs);
  prep_tiles<<<dim3(1312), dim3(256), 0, stream>>>(enc_w, dec_w, e_w1, e_w2, c2s_w,
                                                   BtE, decT, W1T, W2T, c2sT);
  // enc: spikes = sigmoid(X @ enc_w + b), 3x-bf16 split GEMM K=3072, deep-pipelined 256^2
  gemm8<256><<<dim3(256), dim3(512), 0, stream>>>(Axs, BtE, enc_b, spikes, 8192, 2048, 3072);
  // s2c (exact fp32): 16-way K-split partials + reduce
  s2c_split<<<dim3(512), dim3(256), 0, stream>>>(spikes, s2c_w, part);
  s2c_reduce<<<dim3(512), dim3(256), 0, stream>>>(part, s2c_b, cont, contbf);
  // router -> comb[N,8]
  router_kernel<<<dim3(512), dim3(256), 0, stream>>>(cont, r_w1, r_b1, r_w2, r_b2, comb);
  // dense weighted experts -> part (4 slots) -> moe bf16
  expert_kernel<<<dim3(512), dim3(256), 0, stream>>>(contbf, comb, W1T, W2T, e_b1, e_b2, part);
  reduce_moe<<<dim3(2048), dim3(256), 0, stream>>>(part, moebf);
  // c2s: rates = sigmoid(moe @ c2s_w + b) (bf16 out; overwrites Axs after reduce_moe)
  gemm_bt<1,1><<<dim3(64*16), dim3(256), 0, stream>>>(moebf, c2sT, c2s_b, (void*)rates, 8192, 2048, 64);
  // dec: dec = sigmoid(rates @ dec_w + b), deep-pipelined 256x128 (f32 out)
  gemm8<128><<<dim3(256), dim3(512), 0, stream>>>(rates, decT, dec_b, decf, 8192, 1024, 2048);
  // LayerNorm -> out
  ln_kernel<<<dim3(2048), dim3(256), 0, stream>>>(decf, ln_g, ln_b, outp);
}

// Round 11
// 476.606 us; speedup vs baseline: 1.0955x; 1.0955x over previous
//
#include <hip/hip_runtime.h>
#include <hip/hip_bf16.h>
#include <math.h>

// ---------- types & helpers ----------
typedef float  f32x4  __attribute__((ext_vector_type(4)));
typedef __bf16 bf16x8 __attribute__((ext_vector_type(8)));

__device__ __forceinline__ unsigned short f2bf(float f){
  union { float f; unsigned u; } v; v.f = f;
  unsigned u = v.u;
  return (unsigned short)((u + 0x7FFFu + ((u >> 16) & 1u)) >> 16);
}
__device__ __forceinline__ float bf2f(unsigned short h){
  union { unsigned u; float f; } v; v.u = ((unsigned)h) << 16;
  return v.f;
}
__device__ __forceinline__ void gload_lds16(const void* g, void* l){
  __builtin_amdgcn_global_load_lds((__attribute__((address_space(1))) void*)g,
                                   (__attribute__((address_space(3))) void*)l, 16, 0, 0);
}
__device__ __forceinline__ float sigmoidf_(float x){ return 1.f / (1.f + expf(-x)); }

// ---------- prep: split X into [hi | lo | hi] bf16, K 1024 -> 3072 ----------
__global__ __launch_bounds__(256)
void split_x_kernel(const float* __restrict__ X, unsigned short* __restrict__ A){
  for (int i = blockIdx.x*256 + threadIdx.x; i < 8192*1024; i += gridDim.x*256){
    int row = i >> 10, col = i & 1023;
    float x = X[i];
    unsigned short h = f2bf(x);
    unsigned short l = f2bf(x - bf2f(h));
    unsigned short* Ar = A + (size_t)row*3072 + col;
    Ar[0]    = h;   // hi
    Ar[1024] = l;   // lo
    Ar[2048] = h;   // hi (pairs with w_lo)
  }
}

// ---------- prep: LDS-tiled 64x64 transpose/convert for all weights ----------
__global__ __launch_bounds__(256)
void prep_tiles(const float* __restrict__ enc_w, const float* __restrict__ dec_w,
                const float* __restrict__ e_w1, const float* __restrict__ e_w2,
                const float* __restrict__ c2s_w,
                unsigned short* __restrict__ BtE, unsigned short* __restrict__ decT,
                unsigned short* __restrict__ W1T, unsigned short* __restrict__ W2T,
                unsigned short* __restrict__ c2sT)
{
  __shared__ unsigned tile[64*65];   // packed hi|lo<<16, transposed, pad 65
  const int t = threadIdx.x;
  const int b = blockIdx.x;

  const float* src; long sbase; int sld, r0, c0;
  if (b < 512)        { src = enc_w; sbase = 0;                    sld = 2048; r0 = (b>>5)*64;       c0 = (b&31)*64; }
  else if (b < 1024)  { int q=b-512;  src = dec_w; sbase = 0;      sld = 1024; r0 = (q>>4)*64;       c0 = (q&15)*64; }
  else if (b < 1152)  { int q=b-1024; src = e_w1;  sbase = (long)(q>>4)*65536; sld = 1024; r0 = 0;   c0 = (q&15)*64; }
  else if (b < 1280)  { int q=b-1152; src = e_w2;  sbase = (long)(q>>4)*65536; sld = 64;   r0 = (q&15)*64; c0 = 0; }
  else                { int q=b-1280; src = c2s_w; sbase = 0;      sld = 2048; r0 = 0;              c0 = q*64; }

  #pragma unroll
  for (int it = 0; it < 4; ++it){
    int r  = it*16 + (t>>4);
    int c4 = (t&15)*4;
    float4 v = *(const float4*)&src[sbase + (long)(r0+r)*sld + c0 + c4];
    float vv[4] = {v.x, v.y, v.z, v.w};
    #pragma unroll
    for (int e = 0; e < 4; ++e){
      unsigned short h = f2bf(vv[e]);
      unsigned short l = f2bf(vv[e] - bf2f(h));
      tile[(c4+e)*65 + r] = (unsigned)h | ((unsigned)l << 16);
    }
  }
  __syncthreads();

  #pragma unroll
  for (int it = 0; it < 2; ++it){
    int c  = it*32 + (t>>3);
    int kc = (t&7)*8;
    unsigned short hi8[8], lo8[8];
    #pragma unroll
    for (int e = 0; e < 8; ++e){
      unsigned p = tile[c*65 + kc + e];
      hi8[e] = (unsigned short)(p & 0xFFFFu);
      lo8[e] = (unsigned short)(p >> 16);
    }
    if (b < 512){
      unsigned short* dst = BtE + (size_t)(c0 + c)*3072 + r0 + kc;
      *(uint4*)(dst)        = *(const uint4*)hi8;
      *(uint4*)(dst + 1024) = *(const uint4*)hi8;
      *(uint4*)(dst + 2048) = *(const uint4*)lo8;
    } else if (b < 1024){
      *(uint4*)(decT + (size_t)(c0 + c)*2048 + r0 + kc) = *(const uint4*)hi8;
    } else if (b < 1152){
      int e = (b-1024) >> 4;
      *(uint4*)(W1T + ((size_t)e<<16) + (size_t)(c0 + c)*64 + kc) = *(const uint4*)hi8;
    } else if (b < 1280){
      int e = (b-1152) >> 4;
      *(uint4*)(W2T + ((size_t)e<<16) + (size_t)(c0 + c)*1024 + r0 + kc) = *(const uint4*)hi8;
    } else {
      *(uint4*)(c2sT + (size_t)(c0 + c)*64 + kc) = *(const uint4*)hi8;
    }
  }
}

// ---------- deep-pipelined 256xBN GEMM (T3/T4): BK=32, 4-slot circular LDS, ----------
// counted vmcnt (never 0 in steady loop), raw s_barrier, setprio around MFMA.
// ORDER MATTERS: ds_reads FIRST, then STAGE — STAGE-first makes the compiler
// insert vmcnt(0) before the ds_reads (alias hazard) and kills the pipeline
// (measured R10: 103->141us, MfmaUtil 44->30).
template<int BN>
__global__ __launch_bounds__(512)
void gemm8(const unsigned short* __restrict__ A, const unsigned short* __restrict__ Bt,
           const float* __restrict__ bias, float* __restrict__ C,
           int M, int N, int K)
{
  __shared__ alignas(16) char AsB[4][16384];     // [slot][256 rows x 32 bf16 (64B)]
  __shared__ alignas(16) char BsB[4][BN*64];     // [slot][BN rows x 32 bf16]
  const int t = threadIdx.x, w = t >> 6, lane = t & 63;
  const int nbn = N / BN;
  const int qq = gridDim.x >> 3, bid = (int)blockIdx.x;
  const int sbk = (bid & 7) * qq + (bid >> 3);   // bijective XCD swizzle (grid%8==0)
  const int bm = sbk / nbn, bn = sbk % nbn;
  const int wm = w >> 2, wn = w & 3;             // 2 x 4 wave grid
  constexpr int NR = BN / 64;                    // N fragments per wave (col width BN/4)

  f32x4 acc[8][NR];
  #pragma unroll
  for (int m=0;m<8;++m)
    #pragma unroll
    for (int n=0;n<NR;++n) acc[m][n] = (f32x4){0.f,0.f,0.f,0.f};

  const size_t Kb = (size_t)K * 2;
  const char* Ab = (const char*)A  + (size_t)(bm*256) * Kb;
  const char* Bb = (const char*)Bt + (size_t)(bn*BN) * Kb;
  const int nt = K >> 5;

  auto STAGE = [&](int kt){
    char* Ad = AsB[kt & 3]; char* Bd = BsB[kt & 3];
    #pragma unroll
    for (int i = 0; i < 2; ++i){
      int chunk = w*2 + i;
      int row   = chunk*16 + (lane >> 2);
      int sw    = (((lane & 3) ^ ((row >> 1) & 3)) << 4);
      gload_lds16(Ab + (size_t)row*Kb + (size_t)kt*64 + sw, Ad + chunk*1024);
    }
    #pragma unroll
    for (int i = 0; i < BN/128; ++i){
      int chunk = w*(BN/128) + i;
      int row   = chunk*16 + (lane >> 2);
      int sw    = (((lane & 3) ^ ((row >> 1) & 3)) << 4);
      gload_lds16(Bb + (size_t)row*Kb + (size_t)kt*64 + sw, Bd + chunk*1024);
    }
  };

  STAGE(0); STAGE(1); STAGE(2);
  if constexpr (BN == 256) asm volatile("s_waitcnt vmcnt(8)" ::: "memory");
  else                     asm volatile("s_waitcnt vmcnt(6)" ::: "memory");
  __builtin_amdgcn_s_barrier();

  for (int t0 = 0; t0 < nt; ++t0){
    const char* Ar = AsB[t0 & 3];
    const char* Br = BsB[t0 & 3];
    bf16x8 af[8], bg[NR];
    #pragma unroll
    for (int m = 0; m < 8; ++m){
      int ra = wm*128 + m*16 + (lane & 15);
      af[m] = *(const bf16x8*)(Ar + ra*64 + ((((lane>>4) ^ ((ra>>1)&3))) << 4));
    }
    #pragma unroll
    for (int n = 0; n < NR; ++n){
      int rb = wn*(BN/4) + n*16 + (lane & 15);
      bg[n] = *(const bf16x8*)(Br + rb*64 + ((((lane>>4) ^ ((rb>>1)&3))) << 4));
    }
    if (t0 + 3 < nt) STAGE(t0 + 3);        // slot (t0+3)&3 retired at iter t0-1 barrier
    __builtin_amdgcn_s_setprio(1);
    #pragma unroll
    for (int m = 0; m < 8; ++m)
      #pragma unroll
      for (int n = 0; n < NR; ++n)
        acc[m][n] = __builtin_amdgcn_mfma_f32_16x16x32_bf16(af[m], bg[n], acc[m][n], 0, 0, 0);
    __builtin_amdgcn_s_setprio(0);
    // counted wait: retire exactly tile t0+1's loads (issued 3 iters ago)
    if (t0 + 3 < nt){
      if constexpr (BN == 256) asm volatile("s_waitcnt vmcnt(8)" ::: "memory");
      else                     asm volatile("s_waitcnt vmcnt(6)" ::: "memory");
    } else if (t0 + 2 < nt){
      if constexpr (BN == 256) asm volatile("s_waitcnt vmcnt(4)" ::: "memory");
      else                     asm volatile("s_waitcnt vmcnt(3)" ::: "memory");
    } else {
      asm volatile("s_waitcnt vmcnt(0)" ::: "memory");
    }
    __builtin_amdgcn_s_barrier();
  }

  const int mrow0 = bm*256 + wm*128;
  const int ncol0 = bn*BN + wn*(BN/4);
  #pragma unroll
  for (int m = 0; m < 8; ++m){
    int row = mrow0 + m*16 + ((lane>>4)<<2);
    #pragma unroll
    for (int n = 0; n < NR; ++n){
      int col = ncol0 + n*16 + (lane & 15);
      float bv = bias[col];
      #pragma unroll
      for (int r = 0; r < 4; ++r){
        float v = sigmoidf_(acc[m][n][r] + bv);
        C[(size_t)(row + r)*N + col] = v;
      }
    }
  }
}

// ---------- 128x128 bf16 GEMM (m97 structure) for c2s ----------
template<int SIG, int OBF>
__global__ __launch_bounds__(256)
void gemm_bt(const unsigned short* __restrict__ A, const unsigned short* __restrict__ Bt,
             const float* __restrict__ bias, void* __restrict__ C,
             int M, int N, int K)
{
  __shared__ alignas(16) unsigned short As[128*64];
  __shared__ alignas(16) unsigned short Bs[128*64];
  const int t = threadIdx.x;
  const int wid = t >> 6, lane = t & 63;
  const int nbn = N >> 7;
  const int q = gridDim.x >> 3;
  const int bid = (int)blockIdx.x;
  const int sb = (bid & 7) * q + (bid >> 3);
  const int bm = sb / nbn, bn = sb % nbn;
  const int wm = wid >> 1, wn = wid & 1;

  f32x4 acc[4][4];
  #pragma unroll
  for (int i=0;i<4;++i)
    #pragma unroll
    for (int j=0;j<4;++j) acc[i][j] = (f32x4){0.f,0.f,0.f,0.f};

  const size_t Kb = (size_t)K * 2;
  const char* Ab = (const char*)A  + (size_t)(bm*128) * Kb;
  const char* Bb = (const char*)Bt + (size_t)(bn*128) * Kb;

  for (int k0 = 0; k0 < K; k0 += 64){
    #pragma unroll
    for (int i = 0; i < 4; ++i){
      int L  = ((i*4 + wid) << 10) + (lane << 4);
      int r  = L >> 7;
      int cb = L & 127;
      int sb2 = cb ^ ((r & 7) << 4);
      gload_lds16(Ab + (size_t)r*Kb + (size_t)k0*2 + sb2, (char*)As + ((i*4+wid)<<10));
      gload_lds16(Bb + (size_t)r*Kb + (size_t)k0*2 + sb2, (char*)Bs + ((i*4+wid)<<10));
    }
    __syncthreads();
    #pragma unroll
    for (int ks = 0; ks < 64; ks += 32){
      bf16x8 af[4], bg[4];
      const int cb = ks*2 + ((lane >> 4) << 4);
      #pragma unroll
      for (int i = 0; i < 4; ++i){
        int ra = wm*64 + i*16 + (lane & 15);
        af[i] = *(const bf16x8*)((const char*)As + (ra<<7) + (cb ^ ((ra&7)<<4)));
        int rb = wn*64 + i*16 + (lane & 15);
        bg[i] = *(const bf16x8*)((const char*)Bs + (rb<<7) + (cb ^ ((rb&7)<<4)));
      }
      #pragma unroll
      for (int i = 0; i < 4; ++i)
        #pragma unroll
        for (int j = 0; j < 4; ++j)
          acc[i][j] = __builtin_amdgcn_mfma_f32_16x16x32_bf16(af[i], bg[j], acc[i][j], 0, 0, 0);
    }
    __syncthreads();
  }

  const int mrow0 = bm*128 + wm*64;
  const int ncol0 = bn*128 + wn*64;
  #pragma unroll
  for (int i = 0; i < 4; ++i){
    int row = mrow0 + i*16 + ((lane>>4)<<2);
    #pragma unroll
    for (int j = 0; j < 4; ++j){
      int col = ncol0 + j*16 + (lane & 15);
      float bv = bias[col];
      #pragma unroll
      for (int r = 0; r < 4; ++r){
        float v = acc[i][j][r] + bv;
        if (SIG) v = sigmoidf_(v);
        if (OBF) ((unsigned short*)C)[(size_t)(row + r)*N + col] = f2bf(v);
        else     ((float*)C)[(size_t)(row + r)*N + col] = v;
      }
    }
  }
}

// ---------- s2c (exact fp32), lane=token, 16-way K-split ----------
__global__ __launch_bounds__(256)
void s2c_split(const float* __restrict__ spikes, const float* __restrict__ w,
               float* __restrict__ part)
{
  __shared__ float wS[4][64*64];
  const int t = threadIdx.x, wid = t >> 6, lane = t & 63;
  const int tg = blockIdx.x >> 2;
  const int ck = ((blockIdx.x & 3) << 2) | wid;
  const int tok = tg*64 + lane;
  const int k0 = ck * 128;

  float acc[64];
  #pragma unroll
  for (int j=0;j<64;++j) acc[j] = 0.f;

  const float* srow = spikes + (size_t)tok*2048 + k0;
  float* wsp = wS[wid];

  for (int half = 0; half < 2; ++half){
    const float* gsrc = w + (size_t)(k0 + half*64)*64;
    #pragma unroll
    for (int it = 0; it < 16; ++it){
      int idx = (it*64 + lane)*4;
      *(float4*)&wsp[idx] = *(const float4*)&gsrc[idx];
    }
    #pragma unroll 2
    for (int kq = 0; kq < 16; ++kq){
      float4 s4 = *(const float4*)&srow[half*64 + kq*4];
      const float sv[4] = {s4.x, s4.y, s4.z, s4.w};
      #pragma unroll
      for (int ki = 0; ki < 4; ++ki){
        const float* wrow = &wsp[(kq*4+ki)*64];
        #pragma unroll
        for (int j4 = 0; j4 < 16; ++j4){
          float4 wv = *(const float4*)&wrow[j4*4];
          acc[j4*4+0] += sv[ki] * wv.x;
          acc[j4*4+1] += sv[ki] * wv.y;
          acc[j4*4+2] += sv[ki] * wv.z;
          acc[j4*4+3] += sv[ki] * wv.w;
        }
      }
    }
  }
  float* po = part + ((size_t)ck*8192 + tok)*64;
  #pragma unroll
  for (int j4 = 0; j4 < 16; ++j4){
    float4 o; o.x = acc[j4*4+0]; o.y = acc[j4*4+1]; o.z = acc[j4*4+2]; o.w = acc[j4*4+3];
    *(float4*)&po[j4*4] = o;
  }
}

__global__ __launch_bounds__(256)
void s2c_reduce(const float* __restrict__ part, const float* __restrict__ bias,
                float* __restrict__ cont, unsigned short* __restrict__ contbf)
{
  int i4 = blockIdx.x*256 + threadIdx.x;
  int base = i4 * 4;
  float4 a = {0.f,0.f,0.f,0.f};
  #pragma unroll
  for (int c = 0; c < 16; ++c){
    float4 p = *(const float4*)&part[(size_t)c*524288 + base];
    a.x += p.x; a.y += p.y; a.z += p.z; a.w += p.w;
  }
  int j0 = base & 63;
  float4 b = *(const float4*)&bias[j0];
  a.x += b.x; a.y += b.y; a.z += b.z; a.w += b.w;
  *(float4*)&cont[base] = a;
  unsigned short h0 = f2bf(a.x), h1 = f2bf(a.y), h2 = f2bf(a.z), h3 = f2bf(a.w);
  unsigned u0 = ((unsigned)h1 << 16) | h0;
  unsigned u1 = ((unsigned)h3 << 16) | h2;
  uint2 u; u.x = u0; u.y = u1;
  *(uint2*)&contbf[base] = u;
}

// ---------- router: MLP -> logits -> top2 -> renormalized dense comb[N,8] (fp32) ----------
__global__ __launch_bounds__(256)
void router_kernel(const float* __restrict__ cont, const float* __restrict__ w1,
                   const float* __restrict__ b1, const float* __restrict__ w2,
                   const float* __restrict__ b2, float* __restrict__ comb)
{
  __shared__ float w1s[64*64];
  __shared__ float w2s[64*8];
  __shared__ float b1s[64], b2s[8];
  __shared__ float rhs[4][64];
  const int t = threadIdx.x;
  for (int i = t; i < 64*64; i += 256) w1s[i] = w1[i];
  for (int i = t; i < 64*8;  i += 256) w2s[i] = w2[i];
  if (t < 64) b1s[t] = b1[t];
  if (t < 8)  b2s[t] = b2[t];
  __syncthreads();
  const int wid = t >> 6, lane = t & 63;
  const int gw = blockIdx.x*4 + wid, nw = gridDim.x*4;
  for (int n = gw; n < 8192; n += nw){
    float cv = cont[(size_t)n*64 + lane];
    float rh = b1s[lane];
    #pragma unroll
    for (int d = 0; d < 64; ++d){
      float cd = __shfl(cv, d);
      rh += cd * w1s[d*64 + lane];
    }
    rh = fmaxf(rh, 0.f);
    rhs[wid][lane] = rh;
    __syncthreads();
    float lg[8];
    #pragma unroll
    for (int e = 0; e < 8; ++e) lg[e] = b2s[e];
    for (int jj = 0; jj < 64; ++jj){
      float r = rhs[wid][jj];
      #pragma unroll
      for (int e = 0; e < 8; ++e) lg[e] += r * w2s[jj*8 + e];
    }
    int i1 = 0; float m1 = lg[0];
    #pragma unroll
    for (int e = 1; e < 8; ++e) if (lg[e] > m1){ m1 = lg[e]; i1 = e; }
    int i2 = -1; float m2 = -3.4e38f;
    #pragma unroll
    for (int e = 0; e < 8; ++e) if (e != i1 && lg[e] > m2){ m2 = lg[e]; i2 = e; }
    float e2 = expf(m2 - m1);
    float wA = 1.f / (1.f + e2);
    float wB = e2 / (1.f + e2);
    if (lane < 8) comb[(size_t)n*8 + lane] = (lane == i1) ? wA : ((lane == i2) ? wB : 0.f);
    __syncthreads();
  }
}

// ---------- dense fused expert compute (bf16 MFMA), partial over expert-pair groups ----------
__global__ __launch_bounds__(256)
void expert_kernel(const unsigned short* __restrict__ contbf, const float* __restrict__ comb,
                   const unsigned short* __restrict__ W1T, const unsigned short* __restrict__ W2T,
                   const float* __restrict__ e_b1, const float* __restrict__ e_b2,
                   float* __restrict__ part)
{
  __shared__ alignas(16) unsigned short contS[64*64];
  __shared__ alignas(16) unsigned short w1S[64*64];
  __shared__ alignas(16) unsigned short w2S[64*64];
  __shared__ alignas(16) unsigned short ehS[64*64];
  __shared__ float combS[64*8];
  const int t = threadIdx.x, wid = t >> 6, lane = t & 63;
  const int tb = blockIdx.x >> 2, z = blockIdx.x & 3;
  const int tok0 = tb * 64;

  #pragma unroll
  for (int it = 0; it < 2; ++it){
    int li = (it*256 + t)*8;
    int r = li >> 6, c = li & 63;
    uint4 v = *(const uint4*)(contbf + (size_t)(tok0 + r)*64 + c);
    *(uint4*)((char*)contS + (r<<7) + ((c*2) ^ ((r&7)<<4))) = v;
  }
  for (int i = t; i < 512; i += 256) combS[i] = comb[(size_t)tok0*8 + i];

  f32x4 macc[4];
  #pragma unroll
  for (int j=0;j<4;++j) macc[j] = (f32x4){0.f,0.f,0.f,0.f};

  for (int ei = 0; ei < 2; ++ei){
    const int e = z*2 + ei;
    f32x4 eo[4];
    #pragma unroll
    for (int j=0;j<4;++j) eo[j] = (f32x4){0.f,0.f,0.f,0.f};

    for (int hc = 0; hc < 16; ++hc){
      const int h0 = hc*64;
      __syncthreads();
      #pragma unroll
      for (int it = 0; it < 2; ++it){
        int li = (it*256 + t)*8;
        int r = li >> 6, c = li & 63;
        uint4 v1 = *(const uint4*)(W1T + ((size_t)e<<16) + (size_t)(h0+r)*64 + c);
        *(uint4*)((char*)w1S + (r<<7) + ((c*2) ^ ((r&7)<<4))) = v1;
        uint4 v2 = *(const uint4*)(W2T + ((size_t)e<<16) + (size_t)r*1024 + h0 + c);
        *(uint4*)((char*)w2S + (r<<7) + ((c*2) ^ ((r&7)<<4))) = v2;
      }
      __syncthreads();
      f32x4 eh[4];
      #pragma unroll
      for (int j=0;j<4;++j) eh[j] = (f32x4){0.f,0.f,0.f,0.f};
      #pragma unroll
      for (int ks = 0; ks < 64; ks += 32){
        const int cb = ks*2 + ((lane>>4)<<4);
        int ra = wid*16 + (lane & 15);
        bf16x8 av = *(const bf16x8*)((const char*)contS + (ra<<7) + (cb ^ ((ra&7)<<4)));
        #pragma unroll
        for (int j=0;j<4;++j){
          int rb = j*16 + (lane & 15);
          bf16x8 bv = *(const bf16x8*)((const char*)w1S + (rb<<7) + (cb ^ ((rb&7)<<4)));
          eh[j] = __builtin_amdgcn_mfma_f32_16x16x32_bf16(av, bv, eh[j], 0, 0, 0);
        }
      }
      #pragma unroll
      for (int j=0;j<4;++j){
        int colh = j*16 + (lane & 15);
        float b1v = e_b1[e*1024 + h0 + colh];
        #pragma unroll
        for (int r=0;r<4;++r){
          int rowt = wid*16 + ((lane>>4)<<2) + r;
          float v = fmaxf(eh[j][r] + b1v, 0.f);
          *(unsigned short*)((char*)ehS + (rowt<<7) + ((colh*2) ^ ((rowt&7)<<4))) = f2bf(v);
        }
      }
      __syncthreads();
      #pragma unroll
      for (int ks = 0; ks < 64; ks += 32){
        const int cb = ks*2 + ((lane>>4)<<4);
        int ra = wid*16 + (lane & 15);
        bf16x8 av = *(const bf16x8*)((const char*)ehS + (ra<<7) + (cb ^ ((ra&7)<<4)));
        #pragma unroll
        for (int j=0;j<4;++j){
          int rb = j*16 + (lane & 15);
          bf16x8 bv = *(const bf16x8*)((const char*)w2S + (rb<<7) + (cb ^ ((rb&7)<<4)));
          eo[j] = __builtin_amdgcn_mfma_f32_16x16x32_bf16(av, bv, eo[j], 0, 0, 0);
        }
      }
    }
    #pragma unroll
    for (int j=0;j<4;++j){
      int col = j*16 + (lane & 15);
      float b2v = e_b2[e*64 + col];
      #pragma unroll
      for (int r=0;r<4;++r){
        int rowt = wid*16 + ((lane>>4)<<2) + r;
        float w = combS[rowt*8 + e];
        macc[j][r] += w * (eo[j][r] + b2v);
      }
    }
  }
  #pragma unroll
  for (int j=0;j<4;++j){
    int col = j*16 + (lane & 15);
    #pragma unroll
    for (int r=0;r<4;++r){
      int rowt = wid*16 + ((lane>>4)<<2) + r;
      part[((size_t)z*8192 + tok0 + rowt)*64 + col] = macc[j][r];
    }
  }
}

__global__ __launch_bounds__(256)
void reduce_moe(const float* __restrict__ part, unsigned short* __restrict__ moebf){
  int i = blockIdx.x*256 + threadIdx.x;
  if (i < 8192*64){
    float v = part[i] + part[i + 524288] + part[i + 2*524288] + part[i + 3*524288];
    moebf[i] = f2bf(v);
  }
}

// ---------- LayerNorm over dec rows ----------
__global__ __launch_bounds__(256)
void ln_kernel(const float* __restrict__ dec, const float* __restrict__ g,
               const float* __restrict__ b, float* __restrict__ out){
  const int wid = threadIdx.x >> 6, lane = threadIdx.x & 63;
  const int row = blockIdx.x*4 + wid;
  const float4* x4 = (const float4*)(dec + (size_t)row*1024);
  float4 v[4]; float s = 0.f, s2 = 0.f;
  #pragma unroll
  for (int i=0;i<4;++i){
    v[i] = x4[lane + i*64];
    s  += (v[i].x + v[i].y) + (v[i].z + v[i].w);
    s2 += (v[i].x*v[i].x + v[i].y*v[i].y) + (v[i].z*v[i].z + v[i].w*v[i].w);
  }
  #pragma unroll
  for (int o = 32; o > 0; o >>= 1){ s += __shfl_xor(s, o); s2 += __shfl_xor(s2, o); }
  float mu  = s * (1.f/1024.f);
  float var = s2 * (1.f/1024.f) - mu*mu;
  float inv = rsqrtf(var + 1e-5f);
  float4* o4 = (float4*)(out + (size_t)row*1024);
  #pragma unroll
  for (int i=0;i<4;++i){
    int c0 = (lane + i*64)*4;
    float4 r;
    r.x = (v[i].x - mu)*inv*g[c0+0] + b[c0+0];
    r.y = (v[i].y - mu)*inv*g[c0+1] + b[c0+1];
    r.z = (v[i].z - mu)*inv*g[c0+2] + b[c0+2];
    r.w = (v[i].w - mu)*inv*g[c0+3] + b[c0+3];
    o4[lane + i*64] = r;
  }
}

// ---------- launch ----------
extern "C" void kernel_launch(void* const* d_in, const int* in_sizes, int n_in,
                              void* d_out, int out_size, void* d_ws, size_t ws_size,
                              hipStream_t stream)
{
  (void)in_sizes; (void)n_in; (void)out_size; (void)ws_size;
  const float* X     = (const float*)d_in[0];
  const float* enc_w = (const float*)d_in[1];
  const float* enc_b = (const float*)d_in[2];
  const float* s2c_w = (const float*)d_in[3];
  const float* s2c_b = (const float*)d_in[4];
  const float* r_w1  = (const float*)d_in[5];
  const float* r_b1  = (const float*)d_in[6];
  const float* r_w2  = (const float*)d_in[7];
  const float* r_b2  = (const float*)d_in[8];
  const float* e_w1  = (const float*)d_in[9];
  const float* e_b1  = (const float*)d_in[10];
  const float* e_w2  = (const float*)d_in[11];
  const float* e_b2  = (const float*)d_in[12];
  const float* c2s_w = (const float*)d_in[13];
  const float* c2s_b = (const float*)d_in[14];
  const float* dec_w = (const float*)d_in[15];
  const float* dec_b = (const float*)d_in[16];
  const float* ln_g  = (const float*)d_in[17];
  const float* ln_b  = (const float*)d_in[18];

  char* ws = (char*)d_ws;
  size_t off = 0;
  auto alloc = [&](size_t bytes){ void* p = ws + off; off += (bytes + 255) & ~(size_t)255; return p; };
  unsigned short* Axs    = (unsigned short*)alloc(8192ULL*3072*2);  // split X; reused as s2c part & rates
  unsigned short* BtE    = (unsigned short*)alloc(2048ULL*3072*2);
  float*          spikes = (float*)alloc(8192ULL*2048*4);           // later reused as dec f32
  float*          cont   = (float*)alloc(8192ULL*64*4);
  unsigned short* contbf = (unsigned short*)alloc(8192ULL*64*2);
  float*          comb   = (float*)alloc(8192ULL*8*4);
  unsigned short* W1T    = (unsigned short*)alloc(8ULL*1024*64*2);
  unsigned short* W2T    = (unsigned short*)alloc(8ULL*64*1024*2);
  unsigned short* moebf  = (unsigned short*)alloc(8192ULL*64*2);
  unsigned short* c2sT   = (unsigned short*)alloc(2048ULL*64*2);
  unsigned short* decT   = (unsigned short*)alloc(1024ULL*2048*2);
  float*          part   = (float*)Axs;
  unsigned short* rates  = Axs;
  float*          decf   = spikes;
  float*          outp   = (float*)d_out;

  split_x_kernel<<<dim3(4096), dim3(256), 0, stream>>>(X, Axs);
  prep_tiles<<<dim3(1312), dim3(256), 0, stream>>>(enc_w, dec_w, e_w1, e_w2, c2s_w,
                                                   BtE, decT, W1T, W2T, c2sT);
  // enc: spikes = sigmoid(X @ enc_w + b), 3x-bf16 split GEMM K=3072, deep-pipelined 256^2
  gemm8<256><<<dim3(256), dim3(512), 0, stream>>>(Axs, BtE, enc_b, spikes, 8192, 2048, 3072);
  // s2c (exact fp32): 16-way K-split partials + reduce
  s2c_split<<<dim3(512), dim3(256), 0, stream>>>(spikes, s2c_w, part);
  s2c_reduce<<<dim3(512), dim3(256), 0, stream>>>(part, s2c_b, cont, contbf);
  // router -> comb[N,8]
  router_kernel<<<dim3(512), dim3(256), 0, stream>>>(cont, r_w1, r_b1, r_w2, r_b2, comb);
  // dense weighted experts -> part (4 slots) -> moe bf16
  expert_kernel<<<dim3(512), dim3(256), 0, stream>>>(contbf, comb, W1T, W2T, e_b1, e_b2, part);
  reduce_moe<<<dim3(2048), dim3(256), 0, stream>>>(part, moebf);
  // c2s: rates = sigmoid(moe @ c2s_w + b) (bf16 out; overwrites Axs after reduce_moe)
  gemm_bt<1,1><<<dim3(64*16), dim3(256), 0, stream>>>(moebf, c2sT, c2s_b, (void*)rates, 8192, 2048, 64);
  // dec: dec = sigmoid(rates @ dec_w + b), deep-pipelined 256x128 (f32 out)
  gemm8<128><<<dim3(256), dim3(512), 0, stream>>>(rates, decT, dec_b, decf, 8192, 1024, 2048);
  // LayerNorm -> out
  ln_kernel<<<dim3(2048), dim3(256), 0, stream>>>(decf, ln_g, ln_b, outp);
}